// Round 1
// baseline (276.169 us; speedup 1.0000x reference)
//
#include <hip/hip_runtime.h>
#include <hip/hip_bf16.h>

// GAT fused forward loss.
// Structure: e_ij = lrelu(s_i + d_j) is rank-1 => flash-style masked softmax
// aggregation with P built on the fly in bf16, P@Wh via MFMA 16x16x32.
// relu(elu(x)) == relu(x); no softmax max-shift needed (|s+d| < ~8).

#define NN 8192
#define FTDIM 512
#define CDIM 64
#define NTRAIN 1024

typedef __attribute__((ext_vector_type(8))) short short8;
typedef __attribute__((ext_vector_type(4))) float f32x4;
typedef __attribute__((ext_vector_type(4))) int i32x4;

static __device__ __forceinline__ unsigned short f2bf(float x) {
    return __bfloat16_as_ushort(__float2bfloat16(x));
}

// ---------------------------------------------------------------------------
// Kernel A: Wh = feat @ W (8192x512 @ 512x64). Each wave computes 8 rows,
// lane c owns column c. Writes Vt[c][j] = bf16(Wh[j][c]) (transposed so the
// MFMA B-fragment load in kernel B is one contiguous 16B read), and the
// per-node attention scalars s (= Wh@a[:64]) and d (= Wh@a[64:]).
// ---------------------------------------------------------------------------
__global__ __launch_bounds__(256) void k_wh(
    const float* __restrict__ feat, const float* __restrict__ W,
    const float* __restrict__ av, unsigned short* __restrict__ Vt,
    float* __restrict__ sv, float* __restrict__ dv)
{
    const int lane = threadIdx.x & 63;
    const int wv   = (int)((blockIdx.x * blockDim.x + threadIdx.x) >> 6);
    const int row0 = wv * 8;
    const int c    = lane;

    float acc[8];
#pragma unroll
    for (int r = 0; r < 8; ++r) acc[r] = 0.f;

    for (int k = 0; k < FTDIM; k += 4) {
        f32x4 f[8];
#pragma unroll
        for (int r = 0; r < 8; ++r)
            f[r] = *(const f32x4*)(feat + (size_t)(row0 + r) * FTDIM + k);
#pragma unroll
        for (int kk = 0; kk < 4; ++kk) {
            float wval = W[(k + kk) * CDIM + c];
#pragma unroll
            for (int r = 0; r < 8; ++r)
                acc[r] = fmaf(f[r][kk], wval, acc[r]);
        }
    }

    // Vt[c][row0..row0+7] as one 16B store
    short8 v;
#pragma unroll
    for (int r = 0; r < 8; ++r) v[r] = (short)f2bf(acc[r]);
    *(short8*)(Vt + (size_t)c * NN + row0) = v;

    const float a1 = av[c], a2 = av[CDIM + c];
#pragma unroll
    for (int r = 0; r < 8; ++r) {
        float s_ = acc[r] * a1;
        float d_ = acc[r] * a2;
#pragma unroll
        for (int off = 32; off; off >>= 1) {
            s_ += __shfl_xor(s_, off);
            d_ += __shfl_xor(d_, off);
        }
        if (lane == 0) { sv[row0 + r] = s_; dv[row0 + r] = d_; }
    }
}

// ---------------------------------------------------------------------------
// Kernel B: fused masked-softmax aggregation.
// One wave owns a 16-row stripe of one adjacency layer and one j-chunk
// (j-split by 2^scLog2 for occupancy). Per 32-j step: load adj tile (the
// only HBM-heavy stream, each element read exactly once), build
// P = adj ? exp(lrelu(s_i+d_j)) : 0 in bf16 A-fragments, accumulate
// O[16x64] with 4 MFMAs and the row-sum Z on the VALU.
// A-frag layout (16x16x32): lane = (r = m-row [0..15], kg = k-group [0..3]),
// element e -> k = kg*8+e. B-frag: lane&15 = n-col, same k mapping -> Vt row.
// C/D: col = lane&15, row = kg*4 + q  (guide §3, m89-verified).
// ---------------------------------------------------------------------------
__global__ __launch_bounds__(256) void k_attn(
    const int* __restrict__ adj1, const int* __restrict__ adj2,
    const unsigned short* __restrict__ Vt, const float* __restrict__ sv,
    const float* __restrict__ dvec, float* __restrict__ numP,
    float* __restrict__ zP, const int scLog2)
{
    const int lane = threadIdx.x & 63;
    const int w = (int)((blockIdx.x * blockDim.x + threadIdx.x) >> 6);
    const int layer = w >> (9 + scLog2);
    const int rem = w & ((1 << (9 + scLog2)) - 1);
    const int rb = rem >> scLog2;
    const int sc = rem & ((1 << scLog2) - 1);

    const int r  = lane & 15;
    const int kg = lane >> 4;
    const int i  = rb * 16 + r;

    const int jchunk = NN >> scLog2;
    const int jbase  = sc * jchunk + kg * 8;
    const int niter  = jchunk >> 5;

    const int* __restrict__ adj = (layer == 0) ? adj1 : adj2;
    const int*            arow = adj + (size_t)i * NN + jbase;
    const float*          dp   = dvec + jbase;
    const unsigned short* vtp  = Vt + jbase;
    const float s_i = sv[i];

    f32x4 acc0 = {0.f, 0.f, 0.f, 0.f};
    f32x4 acc1 = acc0, acc2 = acc0, acc3 = acc0;
    float z = 0.f;

#pragma unroll 2
    for (int jt = 0; jt < niter; ++jt) {
        const int off = jt * 32;
        i32x4 m0 = *(const i32x4*)(arow + off);
        i32x4 m1 = *(const i32x4*)(arow + off + 4);
        f32x4 d0 = *(const f32x4*)(dp + off);
        f32x4 d1 = *(const f32x4*)(dp + off + 4);
        short8 b0 = *(const short8*)(vtp + (size_t)(r)      * NN + off);
        short8 b1 = *(const short8*)(vtp + (size_t)(16 + r) * NN + off);
        short8 b2 = *(const short8*)(vtp + (size_t)(32 + r) * NN + off);
        short8 b3 = *(const short8*)(vtp + (size_t)(48 + r) * NN + off);

        short8 af;
        float z0 = 0.f;
#pragma unroll
        for (int e = 0; e < 4; ++e) {
            float t = s_i + d0[e];
            float p = __expf(fmaxf(t, 0.2f * t));   // lrelu = max(x, 0.2x)
            p = (m0[e] != 0) ? p : 0.f;
            z0 += p;
            af[e] = (short)f2bf(p);
        }
#pragma unroll
        for (int e = 0; e < 4; ++e) {
            float t = s_i + d1[e];
            float p = __expf(fmaxf(t, 0.2f * t));
            p = (m1[e] != 0) ? p : 0.f;
            z0 += p;
            af[4 + e] = (short)f2bf(p);
        }
        z += z0;

        acc0 = __builtin_amdgcn_mfma_f32_16x16x32_bf16(af, b0, acc0, 0, 0, 0);
        acc1 = __builtin_amdgcn_mfma_f32_16x16x32_bf16(af, b1, acc1, 0, 0, 0);
        acc2 = __builtin_amdgcn_mfma_f32_16x16x32_bf16(af, b2, acc2, 0, 0, 0);
        acc3 = __builtin_amdgcn_mfma_f32_16x16x32_bf16(af, b3, acc3, 0, 0, 0);
    }

    // Z: combine the 4 k-groups of each row (lanes r, r+16, r+32, r+48)
    z += __shfl_xor(z, 16);
    z += __shfl_xor(z, 32);

    const size_t chunkbase = (size_t)((layer << scLog2) + sc) * NN;
    if (kg == 0) zP[chunkbase + i] = z;

    const int orow0 = rb * 16 + kg * 4;
#pragma unroll
    for (int q = 0; q < 4; ++q) {
        float* op = numP + (chunkbase + orow0 + q) * CDIM + r;
        op[0]  = acc0[q];
        op[16] = acc1[q];
        op[32] = acc2[q];
        op[48] = acc3[q];
    }
}

// ---------------------------------------------------------------------------
// Kernel C: per-training-sample loss. One wave per sample, lane = class.
// h = 0.5*(relu(n1/z1) + relu(n2/z2)); log-softmax over 64 lanes; NLL.
// ---------------------------------------------------------------------------
__global__ __launch_bounds__(256) void k_loss(
    const float* __restrict__ numP, const float* __restrict__ zP,
    const int* __restrict__ labels, const int* __restrict__ idxt,
    float* __restrict__ losses, const int SC)
{
    const int lane = threadIdx.x & 63;
    const int k = (int)((blockIdx.x * blockDim.x + threadIdx.x) >> 6);
    const int i = idxt[k];

    float logit = 0.f;
#pragma unroll
    for (int l = 0; l < 2; ++l) {
        float nsum = 0.f, zsum = 0.f;
        for (int s = 0; s < SC; ++s) {
            size_t b = (size_t)(l * SC + s) * NN + i;
            nsum += numP[b * CDIM + lane];
            zsum += zP[b];
        }
        logit += fmaxf(nsum / zsum, 0.f);   // relu(elu(x)) == relu(x)
    }
    logit *= 0.5f;

    float m = logit;
#pragma unroll
    for (int off = 32; off; off >>= 1) m = fmaxf(m, __shfl_xor(m, off));
    float ex = __expf(logit - m);
    float sum = ex;
#pragma unroll
    for (int off = 32; off; off >>= 1) sum += __shfl_xor(sum, off);
    const float logp = logit - m - __logf(sum);

    const int y = labels[i];
    const float t = __shfl(logp, y);
    if (lane == 0) losses[k] = -t;
}

// ---------------------------------------------------------------------------
// Kernel D: mean of 1024 per-sample losses -> d_out[0].
// ---------------------------------------------------------------------------
__global__ __launch_bounds__(256) void k_reduce(
    const float* __restrict__ losses, float* __restrict__ out)
{
    __shared__ float sbuf[4];
    const int tid = threadIdx.x;
    float v = losses[tid] + losses[tid + 256] + losses[tid + 512] + losses[tid + 768];
#pragma unroll
    for (int off = 32; off; off >>= 1) v += __shfl_xor(v, off);
    if ((tid & 63) == 0) sbuf[tid >> 6] = v;
    __syncthreads();
    if (tid == 0) out[0] = (sbuf[0] + sbuf[1] + sbuf[2] + sbuf[3]) * (1.f / 1024.f);
}

// ---------------------------------------------------------------------------
extern "C" void kernel_launch(void* const* d_in, const int* in_sizes, int n_in,
                              void* d_out, int out_size, void* d_ws, size_t ws_size,
                              hipStream_t stream)
{
    const float* feat   = (const float*)d_in[0];
    const float* W      = (const float*)d_in[1];
    const float* av     = (const float*)d_in[2];
    const int*   adj1   = (const int*)d_in[3];
    const int*   adj2   = (const int*)d_in[4];
    const int*   labels = (const int*)d_in[5];
    const int*   idxt   = (const int*)d_in[6];

    // choose j-split from available workspace
    auto needed = [](size_t S) -> size_t {
        return (1u << 20) + (64u << 10)
             + 2 * S * NN * sizeof(float)               // zP
             + 2 * S * (size_t)NN * CDIM * sizeof(float) // numP
             + NTRAIN * sizeof(float);
    };
    int scLog2 = 2;
    if (ws_size < needed(4)) scLog2 = (ws_size >= needed(2)) ? 1 : 0;
    const int SC = 1 << scLog2;

    char* ws = (char*)d_ws;
    unsigned short* Vt = (unsigned short*)ws;                       // 1 MB
    float* sv   = (float*)(ws + (1u << 20));                        // 32 KB
    float* dv   = (float*)(ws + (1u << 20) + (32u << 10));          // 32 KB
    float* zP   = (float*)(ws + (1u << 20) + (64u << 10));
    float* numP = (float*)((char*)zP + 2 * SC * NN * sizeof(float));
    float* losses = (float*)((char*)numP + 2 * (size_t)SC * NN * CDIM * sizeof(float));

    hipLaunchKernelGGL(k_wh, dim3(256), dim3(256), 0, stream,
                       feat, W, av, Vt, sv, dv);
    hipLaunchKernelGGL(k_attn, dim3(256 * SC), dim3(256), 0, stream,
                       adj1, adj2, Vt, sv, dv, numP, zP, scLog2);
    hipLaunchKernelGGL(k_loss, dim3(NTRAIN / 4), dim3(256), 0, stream,
                       numP, zP, labels, idxt, losses, SC);
    hipLaunchKernelGGL(k_reduce, dim3(1), dim3(256), 0, stream,
                       losses, (float*)d_out);
}

// Round 2
// 274.292 us; speedup vs baseline: 1.0068x; 1.0068x over previous
//
#include <hip/hip_runtime.h>
#include <hip/hip_bf16.h>

// GAT fused forward loss.
// e_ij = lrelu(s_i + d_j) is rank-1 => flash-style masked softmax aggregation
// with P built on the fly in bf16, P@Wh via MFMA 16x16x32.
// relu(elu(x)) == relu(x); no softmax max-shift needed (|s+d| < ~8).
// R2: software-pipelined k_attn (prefetch next tile before computing current)
//     to fix latency-bound 14%-HBM; s,d pre-scaled by log2(e) -> bare v_exp.

#define NN 8192
#define FTDIM 512
#define CDIM 64
#define NTRAIN 1024
#define LOG2E 1.44269504088896f

typedef __attribute__((ext_vector_type(8))) short short8;
typedef __attribute__((ext_vector_type(4))) float f32x4;
typedef __attribute__((ext_vector_type(4))) int i32x4;

static __device__ __forceinline__ unsigned short f2bf(float x) {
    return __bfloat16_as_ushort(__float2bfloat16(x));
}

// ---------------------------------------------------------------------------
// Kernel A: Wh = feat @ W (8192x512 @ 512x64). Each wave computes 8 rows,
// lane c owns column c. Writes Vt[c][j] = bf16(Wh[j][c]) and per-node
// attention scalars s,d PRE-SCALED by log2(e) (lrelu commutes with the
// positive scale, so exp(lrelu(s+d)) == exp2(lrelu(s'+d'))).
// ---------------------------------------------------------------------------
__global__ __launch_bounds__(256) void k_wh(
    const float* __restrict__ feat, const float* __restrict__ W,
    const float* __restrict__ av, unsigned short* __restrict__ Vt,
    float* __restrict__ sv, float* __restrict__ dv)
{
    const int lane = threadIdx.x & 63;
    const int wv   = (int)((blockIdx.x * blockDim.x + threadIdx.x) >> 6);
    const int row0 = wv * 8;
    const int c    = lane;

    float acc[8];
#pragma unroll
    for (int r = 0; r < 8; ++r) acc[r] = 0.f;

    for (int k = 0; k < FTDIM; k += 4) {
        f32x4 f[8];
#pragma unroll
        for (int r = 0; r < 8; ++r)
            f[r] = *(const f32x4*)(feat + (size_t)(row0 + r) * FTDIM + k);
#pragma unroll
        for (int kk = 0; kk < 4; ++kk) {
            float wval = W[(k + kk) * CDIM + c];
#pragma unroll
            for (int r = 0; r < 8; ++r)
                acc[r] = fmaf(f[r][kk], wval, acc[r]);
        }
    }

    short8 v;
#pragma unroll
    for (int r = 0; r < 8; ++r) v[r] = (short)f2bf(acc[r]);
    *(short8*)(Vt + (size_t)c * NN + row0) = v;

    const float a1 = av[c], a2 = av[CDIM + c];
#pragma unroll
    for (int r = 0; r < 8; ++r) {
        float s_ = acc[r] * a1;
        float d_ = acc[r] * a2;
#pragma unroll
        for (int off = 32; off; off >>= 1) {
            s_ += __shfl_xor(s_, off);
            d_ += __shfl_xor(d_, off);
        }
        if (lane == 0) { sv[row0 + r] = s_ * LOG2E; dv[row0 + r] = d_ * LOG2E; }
    }
}

// ---------------------------------------------------------------------------
// Kernel B: fused masked-softmax aggregation, 2-stage software pipeline.
// One wave owns a 16-row stripe of one layer and one j-chunk. Per 32-j tile:
// 8 loads (2x adj i32x4 [the only HBM stream], 2x d f32x4 [broadcast/L1],
// 4x Vt short8 [L2]); P = adj ? exp2(lrelu(s'+d')) : 0 in bf16 A-frags;
// 4 MFMAs + VALU row-sum Z. Prefetching tile jt+1 before computing jt keeps
// ~6 KB/wave outstanding -> with 16 waves/CU far above the ~9.3 KB/CU needed
// for full HBM BW. No barriers => compiler emits counted vmcnt, no drain.
// A/B/C/D fragment layouts as in R1 (verified passing).
// ---------------------------------------------------------------------------
struct Tile {
    i32x4 m0, m1;
    f32x4 d0, d1;
    short8 b0, b1, b2, b3;
};

#define LOADT(T, JT) do { const int _off = (JT) * 32;                          \
    T.m0 = *(const i32x4*)(arow + _off);                                       \
    T.m1 = *(const i32x4*)(arow + _off + 4);                                   \
    T.d0 = *(const f32x4*)(dp + _off);                                         \
    T.d1 = *(const f32x4*)(dp + _off + 4);                                     \
    T.b0 = *(const short8*)(vtp + (size_t)(r) * NN + _off);                    \
    T.b1 = *(const short8*)(vtp + (size_t)(16 + r) * NN + _off);               \
    T.b2 = *(const short8*)(vtp + (size_t)(32 + r) * NN + _off);               \
    T.b3 = *(const short8*)(vtp + (size_t)(48 + r) * NN + _off);               \
} while (0)

#define COMPUTE(T) do {                                                        \
    short8 af; float z0 = 0.f;                                                 \
    _Pragma("unroll")                                                          \
    for (int e = 0; e < 4; ++e) {                                              \
        float t = s_i + T.d0[e];                                               \
        float p = __builtin_amdgcn_exp2f(fmaxf(t, 0.2f * t));                  \
        p = (T.m0[e] != 0) ? p : 0.f;                                          \
        z0 += p; af[e] = (short)f2bf(p);                                       \
    }                                                                          \
    _Pragma("unroll")                                                          \
    for (int e = 0; e < 4; ++e) {                                              \
        float t = s_i + T.d1[e];                                               \
        float p = __builtin_amdgcn_exp2f(fmaxf(t, 0.2f * t));                  \
        p = (T.m1[e] != 0) ? p : 0.f;                                          \
        z0 += p; af[4 + e] = (short)f2bf(p);                                   \
    }                                                                          \
    z += z0;                                                                   \
    acc0 = __builtin_amdgcn_mfma_f32_16x16x32_bf16(af, T.b0, acc0, 0, 0, 0);   \
    acc1 = __builtin_amdgcn_mfma_f32_16x16x32_bf16(af, T.b1, acc1, 0, 0, 0);   \
    acc2 = __builtin_amdgcn_mfma_f32_16x16x32_bf16(af, T.b2, acc2, 0, 0, 0);   \
    acc3 = __builtin_amdgcn_mfma_f32_16x16x32_bf16(af, T.b3, acc3, 0, 0, 0);   \
} while (0)

__global__ __launch_bounds__(256) void k_attn(
    const int* __restrict__ adj1, const int* __restrict__ adj2,
    const unsigned short* __restrict__ Vt, const float* __restrict__ sv,
    const float* __restrict__ dvec, float* __restrict__ numP,
    float* __restrict__ zP, const int scLog2)
{
    const int lane = threadIdx.x & 63;
    const int w = (int)((blockIdx.x * blockDim.x + threadIdx.x) >> 6);
    const int layer = w >> (9 + scLog2);
    const int rem = w & ((1 << (9 + scLog2)) - 1);
    const int rb = rem >> scLog2;
    const int sc = rem & ((1 << scLog2) - 1);

    const int r  = lane & 15;
    const int kg = lane >> 4;
    const int i  = rb * 16 + r;

    const int jchunk = NN >> scLog2;
    const int jbase  = sc * jchunk + kg * 8;
    const int niter  = jchunk >> 5;          // even (>= 64 for scLog2<=2)

    const int* __restrict__ adj = (layer == 0) ? adj1 : adj2;
    const int*            arow = adj + (size_t)i * NN + jbase;
    const float*          dp   = dvec + jbase;
    const unsigned short* vtp  = Vt + jbase;
    const float s_i = sv[i];

    f32x4 acc0 = {0.f, 0.f, 0.f, 0.f};
    f32x4 acc1 = acc0, acc2 = acc0, acc3 = acc0;
    float z = 0.f;

    Tile tA, tB;
    LOADT(tA, 0);
    for (int jt = 0; jt < niter - 2; jt += 2) {
        LOADT(tB, jt + 1);
        COMPUTE(tA);
        LOADT(tA, jt + 2);
        COMPUTE(tB);
    }
    LOADT(tB, niter - 1);
    COMPUTE(tA);
    COMPUTE(tB);

    // Z: combine the 4 k-groups of each row (lanes r, r+16, r+32, r+48)
    z += __shfl_xor(z, 16);
    z += __shfl_xor(z, 32);

    const size_t chunkbase = (size_t)((layer << scLog2) + sc) * NN;
    if (kg == 0) zP[chunkbase + i] = z;

    const int orow0 = rb * 16 + kg * 4;
#pragma unroll
    for (int q = 0; q < 4; ++q) {
        float* op = numP + (chunkbase + orow0 + q) * CDIM + r;
        op[0]  = acc0[q];
        op[16] = acc1[q];
        op[32] = acc2[q];
        op[48] = acc3[q];
    }
}

// ---------------------------------------------------------------------------
// Kernel C: per-training-sample loss. One wave per sample, lane = class.
// h = 0.5*(relu(n1/z1) + relu(n2/z2)); log-softmax over 64 lanes; NLL.
// ---------------------------------------------------------------------------
__global__ __launch_bounds__(256) void k_loss(
    const float* __restrict__ numP, const float* __restrict__ zP,
    const int* __restrict__ labels, const int* __restrict__ idxt,
    float* __restrict__ losses, const int SC)
{
    const int lane = threadIdx.x & 63;
    const int k = (int)((blockIdx.x * blockDim.x + threadIdx.x) >> 6);
    const int i = idxt[k];

    float logit = 0.f;
#pragma unroll
    for (int l = 0; l < 2; ++l) {
        float nsum = 0.f, zsum = 0.f;
        for (int s = 0; s < SC; ++s) {
            size_t b = (size_t)(l * SC + s) * NN + i;
            nsum += numP[b * CDIM + lane];
            zsum += zP[b];
        }
        logit += fmaxf(nsum / zsum, 0.f);   // relu(elu(x)) == relu(x)
    }
    logit *= 0.5f;

    float m = logit;
#pragma unroll
    for (int off = 32; off; off >>= 1) m = fmaxf(m, __shfl_xor(m, off));
    float ex = __expf(logit - m);
    float sum = ex;
#pragma unroll
    for (int off = 32; off; off >>= 1) sum += __shfl_xor(sum, off);
    const float logp = logit - m - __logf(sum);

    const int y = labels[i];
    const float t = __shfl(logp, y);
    if (lane == 0) losses[k] = -t;
}

// ---------------------------------------------------------------------------
// Kernel D: mean of 1024 per-sample losses -> d_out[0].
// ---------------------------------------------------------------------------
__global__ __launch_bounds__(256) void k_reduce(
    const float* __restrict__ losses, float* __restrict__ out)
{
    __shared__ float sbuf[4];
    const int tid = threadIdx.x;
    float v = losses[tid] + losses[tid + 256] + losses[tid + 512] + losses[tid + 768];
#pragma unroll
    for (int off = 32; off; off >>= 1) v += __shfl_xor(v, off);
    if ((tid & 63) == 0) sbuf[tid >> 6] = v;
    __syncthreads();
    if (tid == 0) out[0] = (sbuf[0] + sbuf[1] + sbuf[2] + sbuf[3]) * (1.f / 1024.f);
}

// ---------------------------------------------------------------------------
extern "C" void kernel_launch(void* const* d_in, const int* in_sizes, int n_in,
                              void* d_out, int out_size, void* d_ws, size_t ws_size,
                              hipStream_t stream)
{
    const float* feat   = (const float*)d_in[0];
    const float* W      = (const float*)d_in[1];
    const float* av     = (const float*)d_in[2];
    const int*   adj1   = (const int*)d_in[3];
    const int*   adj2   = (const int*)d_in[4];
    const int*   labels = (const int*)d_in[5];
    const int*   idxt   = (const int*)d_in[6];

    auto needed = [](size_t S) -> size_t {
        return (1u << 20) + (64u << 10)
             + 2 * S * NN * sizeof(float)
             + 2 * S * (size_t)NN * CDIM * sizeof(float)
             + NTRAIN * sizeof(float);
    };
    int scLog2 = 2;
    if (ws_size < needed(4)) scLog2 = (ws_size >= needed(2)) ? 1 : 0;
    const int SC = 1 << scLog2;

    char* ws = (char*)d_ws;
    unsigned short* Vt = (unsigned short*)ws;                       // 1 MB
    float* sv   = (float*)(ws + (1u << 20));
    float* dv   = (float*)(ws + (1u << 20) + (32u << 10));
    float* zP   = (float*)(ws + (1u << 20) + (64u << 10));
    float* numP = (float*)((char*)zP + 2 * SC * NN * sizeof(float));
    float* losses = (float*)((char*)numP + 2 * (size_t)SC * NN * CDIM * sizeof(float));

    hipLaunchKernelGGL(k_wh, dim3(256), dim3(256), 0, stream,
                       feat, W, av, Vt, sv, dv);
    hipLaunchKernelGGL(k_attn, dim3(256 * SC), dim3(256), 0, stream,
                       adj1, adj2, Vt, sv, dv, numP, zP, scLog2);
    hipLaunchKernelGGL(k_loss, dim3(NTRAIN / 4), dim3(256), 0, stream,
                       numP, zP, labels, idxt, losses, SC);
    hipLaunchKernelGGL(k_reduce, dim3(1), dim3(256), 0, stream,
                       losses, (float*)d_out);
}